// Round 8
// baseline (234.881 us; speedup 1.0000x reference)
//
#include <hip/hip_runtime.h>
#include <math.h>

// ---------------------------------------------------------------------------
// SiameseRPN one-branch, round 8 (= round 7 + WFP layout transpose):
//  k_fold: WFP[2][128 eh][4608 k] partial fold (w_merge into w_template).
//          2304 blocks, 16 float4 loads in flight, COALESCED float4 stores
//          (was 4B-per-512B scatter -> cross-XCD partial-line RMW).
//  k0    : pad target_feat -> tfp[512][34][34]; zero tP[256][38][40]; Bfold.
//  k_conv: 3x3 conv partials, K-split x16 -> CVP[16][256][32][32].
//  k_cred: sum 16 slabs + bias + BN + 0.1 -> tP interior.
//  k2    : Z2 partials (row-major WFP reads, sums the two slabs on load).
//  k3    : merged = sum t' * Z2.   k4: heads + softmax.
// Workspace: 6,887,552 floats = 27.6 MB.
// ---------------------------------------------------------------------------

#define WS_TFP 0            // 591872
#define WS_TP  591872       // 389120  -> 980992
#define WS_BF  980992       // 128     -> 981120
#define WS_WFP 981120       // 2*589824 -> 2160768   layout: [half][eh][4608]
#define WS_Z2P 2160768      // 401408  -> 2562176
#define WS_MRG 2562176      // 131072  -> 2693248
#define WS_CVP 2693248      // 16*262144 -> 6887552
#define WFP_HALF 589824

typedef float f4u __attribute__((ext_vector_type(4), aligned(4)));

#define FMA4(ww, vv) \
  acc.x = fmaf(ww, (vv).x, acc.x); acc.y = fmaf(ww, (vv).y, acc.y); \
  acc.z = fmaf(ww, (vv).z, acc.z); acc.w = fmaf(ww, (vv).w, acc.w)

__global__ __launch_bounds__(256) void k_fold(
    const float* __restrict__ wtpl,    // w_template 16384*4608
    const float* __restrict__ wm,      // w_merge_cls 256
    float* ws)
{
  const int bid = blockIdx.x;
  const int g = bid / 18, rest = bid % 18;
  const int chunk = rest >> 1, half = rest & 1;
  const int tid = threadIdx.x;
  const int colv = tid & 127, rowg = tid >> 7;
  const int c0 = chunk * 512 + colv * 4;
  const int row0 = g * 128 + half * 64 + rowg * 32;
  const float* base = wtpl + (size_t)row0 * 4608 + c0;
  const float* wmb = wm + (g & 1) * 128 + half * 64 + rowg * 32;
  float4 acc = make_float4(0.f, 0.f, 0.f, 0.f);
  #pragma unroll
  for (int rr = 0; rr < 32; rr += 16) {
    const float* b = base + (size_t)rr * 4608;
    const float4 v0  = *(const float4*)(b);
    const float4 v1  = *(const float4*)(b + 1 * 4608);
    const float4 v2  = *(const float4*)(b + 2 * 4608);
    const float4 v3  = *(const float4*)(b + 3 * 4608);
    const float4 v4  = *(const float4*)(b + 4 * 4608);
    const float4 v5  = *(const float4*)(b + 5 * 4608);
    const float4 v6  = *(const float4*)(b + 6 * 4608);
    const float4 v7  = *(const float4*)(b + 7 * 4608);
    const float4 v8  = *(const float4*)(b + 8 * 4608);
    const float4 v9  = *(const float4*)(b + 9 * 4608);
    const float4 v10 = *(const float4*)(b + 10 * 4608);
    const float4 v11 = *(const float4*)(b + 11 * 4608);
    const float4 v12 = *(const float4*)(b + 12 * 4608);
    const float4 v13 = *(const float4*)(b + 13 * 4608);
    const float4 v14 = *(const float4*)(b + 14 * 4608);
    const float4 v15 = *(const float4*)(b + 15 * 4608);
    const float w0 = wmb[rr + 0],  w1 = wmb[rr + 1];
    const float w2 = wmb[rr + 2],  w3 = wmb[rr + 3];
    const float w4 = wmb[rr + 4],  w5 = wmb[rr + 5];
    const float w6 = wmb[rr + 6],  w7 = wmb[rr + 7];
    const float w8 = wmb[rr + 8],  w9 = wmb[rr + 9];
    const float w10 = wmb[rr + 10], w11 = wmb[rr + 11];
    const float w12 = wmb[rr + 12], w13 = wmb[rr + 13];
    const float w14 = wmb[rr + 14], w15 = wmb[rr + 15];
    FMA4(w0, v0);   FMA4(w1, v1);   FMA4(w2, v2);   FMA4(w3, v3);
    FMA4(w4, v4);   FMA4(w5, v5);   FMA4(w6, v6);   FMA4(w7, v7);
    FMA4(w8, v8);   FMA4(w9, v9);   FMA4(w10, v10); FMA4(w11, v11);
    FMA4(w12, v12); FMA4(w13, v13); FMA4(w14, v14); FMA4(w15, v15);
  }
  __shared__ float4 red[128];
  if (rowg) red[colv] = acc;
  __syncthreads();
  if (!rowg) {
    const float4 o = red[colv];
    acc.x += o.x; acc.y += o.y; acc.z += o.z; acc.w += o.w;
    // [half][eh][k] layout: lanes write contiguous 1KB -> fully coalesced
    float* wp = ws + WS_WFP + (size_t)half * WFP_HALF + (size_t)g * 4608;
    *(float4*)(wp + c0) = acc;
  }
}

__global__ __launch_bounds__(256) void k0_prep(
    const float* __restrict__ tfeat,   // target_feat 512*32*32
    const float* __restrict__ wm,      // w_merge_cls 256
    const float* __restrict__ btpl,    // b_template 16384
    float* ws)
{
  const int N0 = 591872, N2 = 389120;
  const int total = N0 + N2;
  for (int idx = blockIdx.x * 256 + threadIdx.x; idx < total + 128; idx += gridDim.x * 256) {
    if (idx < N0) {
      int ci = idx / 1156, r = idx % 1156;
      int yy = r / 34, xx = r % 34;
      float v = 0.f;
      if (yy >= 1 && yy <= 32 && xx >= 1 && xx <= 32)
        v = tfeat[ci * 1024 + (yy - 1) * 32 + (xx - 1)];
      ws[WS_TFP + idx] = v;
    } else if (idx < total) {
      ws[WS_TP + (idx - N0)] = 0.f;
    } else {
      const int eh = idx - total;
      const int e = eh >> 1, h = eh & 1;
      const float* wmp = wm + h * 128;
      const float* bp = btpl + e * 256 + h * 128;
      float s = 0.f;
      for (int cl = 0; cl < 128; cl++) s = fmaf(wmp[cl], bp[cl], s);
      ws[WS_BF + eh] = s;
    }
  }
}

__global__ __launch_bounds__(256) void k_conv(
    const float* __restrict__ wtgt,    // w_target 256*512*9
    float* ws)
{
  // grid: coblk(16) x pxblk(16) x ks(8); thread: ksub(2) x cog(4) x pxg(32)
  const int bid = blockIdx.x;
  const int coblk = bid >> 7, pxblk = (bid >> 3) & 15, ks = bid & 7;
  const int tid = threadIdx.x;
  const int ksub = tid >> 7, sub = tid & 127;
  const int cog = sub >> 5, pxg = sub & 31;
  const int row = pxg >> 4, x0 = (pxg & 15) * 2;
  const int y = pxblk * 2 + row;
  const int co0 = coblk * 16 + cog * 4;
  const int ci0 = ks * 64 + ksub * 32;
  const float* tfp = ws + WS_TFP;

  float acc[4][2] = {{0.f, 0.f}, {0.f, 0.f}, {0.f, 0.f}, {0.f, 0.f}};
  for (int i = 0; i < 32; i++) {
    const int ci = ci0 + i;
    const float* tin = tfp + (size_t)ci * 1156 + y * 34 + x0;
    const f4u p0 = *(const f4u*)(tin);
    const f4u p1 = *(const f4u*)(tin + 34);
    const f4u p2 = *(const f4u*)(tin + 68);
    #pragma unroll
    for (int c = 0; c < 4; c++) {
      const float* wr = wtgt + (size_t)(co0 + c) * 4608 + ci * 9;
      const f4u wa = *(const f4u*)(wr);
      const f4u wb = *(const f4u*)(wr + 4);
      const float w8 = wr[8];
      acc[c][0] += wa.x * p0.x + wa.y * p0.y + wa.z * p0.z
                 + wa.w * p1.x + wb.x * p1.y + wb.y * p1.z
                 + wb.z * p2.x + wb.w * p2.y + w8 * p2.z;
      acc[c][1] += wa.x * p0.y + wa.y * p0.z + wa.z * p0.w
                 + wa.w * p1.y + wb.x * p1.z + wb.y * p1.w
                 + wb.z * p2.y + wb.w * p2.z + w8 * p2.w;
    }
  }
  float* cvp = ws + WS_CVP + (size_t)(ks * 2 + ksub) * 262144;
  #pragma unroll
  for (int c = 0; c < 4; c++) {
    cvp[(co0 + c) * 1024 + y * 32 + x0 + 0] = acc[c][0];
    cvp[(co0 + c) * 1024 + y * 32 + x0 + 1] = acc[c][1];
  }
}

__global__ __launch_bounds__(256) void k_cred(
    const float* __restrict__ btgt,
    const float* __restrict__ gamma, const float* __restrict__ beta,
    const float* __restrict__ mean, const float* __restrict__ var,
    float* ws)
{
  const int co = blockIdx.x;
  const int tid = threadIdx.x;
  const float sc = gamma[co] * rsqrtf(var[co] + 1e-5f);
  const float off = btgt[co] - mean[co];
  const float bt = beta[co];
  const float* cvp = ws + WS_CVP + (size_t)co * 1024;
  float* tP = ws + WS_TP;
  #pragma unroll
  for (int k = 0; k < 4; k++) {
    const int j = k * 256 + tid;
    float s = 0.f;
    #pragma unroll
    for (int sl = 0; sl < 16; sl++) s += cvp[(size_t)sl * 262144 + j];
    const float t = ((s + off) * sc + bt) * 0.1f;
    const int yy = j >> 5, xx = j & 31;
    tP[co * 1520 + (yy + 3) * 40 + (xx + 3)] = t;
  }
}

__global__ __launch_bounds__(256) void k2_z2(
    const float* __restrict__ zfeat,    // template_feat 2*512*49
    float* ws)
{
  __shared__ float Tl[50][144];
  const int tid = threadIdx.x;
  const int n = blockIdx.x >> 5, kc = blockIdx.x & 31;
  const int ci0 = kc * 16;
  for (int idx = tid; idx < 7200; idx += 256) {
    const int uv = idx / 144, kk = idx % 144;
    float v = 0.f;
    if (uv < 49) {
      const int u = uv / 7, vv = uv % 7;
      const int ci = ci0 + kk / 9, pq = kk % 9;
      const int p = pq / 3, q = pq % 3;
      const int yy = u + p - 1, xx = vv + q - 1;
      if (yy >= 0 && yy < 7 && xx >= 0 && xx < 7)
        v = zfeat[n * 25088 + ci * 49 + yy * 7 + xx];
    }
    Tl[uv][kk] = v;
  }
  __syncthreads();
  const int ehq = tid & 31, uvg = tid >> 5;
  const int eh0 = ehq * 4;
  const int uv0 = (uvg == 0) ? 0 : uvg * 6 + 1;
  const float* wfp = ws + WS_WFP;
  float4 acc[7];
  #pragma unroll
  for (int i = 0; i < 7; i++) acc[i] = make_float4(0.f, 0.f, 0.f, 0.f);
  for (int g = 0; g < 36; g++) {
    const int koff = ci0 * 9 + g * 4;
    // row-major WFP: wvE[e] = Wfold[eh0+e][koff..koff+3] (slab0 + slab1)
    float4 wvE[4];
    #pragma unroll
    for (int e = 0; e < 4; e++) {
      const float* pe = wfp + (size_t)(eh0 + e) * 4608 + koff;
      float4 a = *(const float4*)(pe);
      const float4 b2 = *(const float4*)(pe + WFP_HALF);
      a.x += b2.x; a.y += b2.y; a.z += b2.z; a.w += b2.w;
      wvE[e] = a;
    }
    #pragma unroll
    for (int uu = 0; uu < 7; uu++) {
      const float4 t4 = *(const float4*)(&Tl[uv0 + uu][g * 4]);
      acc[uu].x = fmaf(t4.x, wvE[0].x, fmaf(t4.y, wvE[0].y, fmaf(t4.z, wvE[0].z, fmaf(t4.w, wvE[0].w, acc[uu].x))));
      acc[uu].y = fmaf(t4.x, wvE[1].x, fmaf(t4.y, wvE[1].y, fmaf(t4.z, wvE[1].z, fmaf(t4.w, wvE[1].w, acc[uu].y))));
      acc[uu].z = fmaf(t4.x, wvE[2].x, fmaf(t4.y, wvE[2].y, fmaf(t4.z, wvE[2].z, fmaf(t4.w, wvE[2].w, acc[uu].z))));
      acc[uu].w = fmaf(t4.x, wvE[3].x, fmaf(t4.y, wvE[3].y, fmaf(t4.z, wvE[3].z, fmaf(t4.w, wvE[3].w, acc[uu].w))));
    }
  }
  float* z2p = ws + WS_Z2P;
  #pragma unroll
  for (int uu = 0; uu < 7; uu++) {
    const int uv = uv0 + uu;
    if (uv <= 48)
      *(float4*)(z2p + ((size_t)((n * 32 + kc) * 49 + uv)) * 128 + eh0) = acc[uu];
  }
}

__global__ __launch_bounds__(128) void k3_merged(float* ws)
{
  __shared__ float Z2s[16][7][8];
  const int tid = threadIdx.x;
  const int bid = blockIdx.x;
  const int n = bid >> 7, rest = bid & 127;
  const int ec = rest >> 4, hq = rest & 15;
  const int c0 = ec * 16, h0 = hq * 2;
  const float* z2p = ws + WS_Z2P;
  const float* bf = ws + WS_BF;
  for (int idx = tid; idx < 784; idx += 128) {
    const int cl = idx & 15, uv = idx >> 4;
    float s = bf[c0 + cl];
    const float* p = z2p + (size_t)(n * 1568 + uv) * 128 + (c0 + cl);
    #pragma unroll 8
    for (int kc = 0; kc < 32; kc++) s += p[(size_t)kc * 6272];
    Z2s[cl][uv / 7][uv % 7] = s;
  }
  for (int idx = tid; idx < 112; idx += 128)
    Z2s[idx / 7][idx % 7][7] = 0.f;
  __syncthreads();

  const int e = tid >> 4, row = (tid >> 3) & 1, wq = tid & 7;
  const int w0 = wq * 4;
  const float* tP = ws + WS_TP;
  float acc[4] = {0.f, 0.f, 0.f, 0.f};
  #pragma unroll
  for (int h128 = 0; h128 < 2; h128++) {
    const int cl = 2 * e + h128;
    const float* tc = tP + (size_t)(128 * n + c0 + cl) * 1520;
    #pragma unroll
    for (int u = 0; u < 7; u++) {
      const float* trow = tc + (h0 + row + u) * 40 + w0;
      float tw[12];
      *(float4*)&tw[0] = *(const float4*)(trow);
      *(float4*)&tw[4] = *(const float4*)(trow + 4);
      *(float4*)&tw[8] = *(const float4*)(trow + 8);
      float z[8];
      *(float4*)&z[0] = *(const float4*)&Z2s[cl][u][0];
      *(float4*)&z[4] = *(const float4*)&Z2s[cl][u][4];
      #pragma unroll
      for (int px = 0; px < 4; px++)
        #pragma unroll
        for (int v = 0; v < 8; v++)
          acc[px] = fmaf(z[v], tw[px + v], acc[px]);
    }
  }
  float* mrg = ws + WS_MRG;
  *(float4*)(mrg + (size_t)(((n * 64 + ec * 8 + e) * 32) + h0 + row) * 32 + w0) =
      make_float4(acc[0], acc[1], acc[2], acc[3]);
}

__global__ __launch_bounds__(256) void k4_heads(
    const float* __restrict__ cb,
    const float* __restrict__ wcls, const float* __restrict__ bcls,
    const float* __restrict__ wbox, const float* __restrict__ bbox,
    float* ws, float* __restrict__ out)
{
  __shared__ float mrg_l[32][66];
  __shared__ float wcb_l[54][64];
  __shared__ float bias_l[54];
  __shared__ float logits[18][32];
  const int tid = threadIdx.x;
  const int n = blockIdx.x >> 5, h = blockIdx.x & 31;
  const float* mrg = ws + WS_MRG;
  for (int idx = tid; idx < 2048; idx += 256) {
    const int e = idx >> 5, w = idx & 31;
    mrg_l[w][e] = mrg[(size_t)(((n * 64 + e) * 32) + h) * 32 + w] + cb[e];
  }
  for (int idx = tid; idx < 3456; idx += 256) {
    const int ch = idx >> 6, e = idx & 63;
    wcb_l[ch][e] = (ch < 18) ? wcls[ch * 64 + e] : wbox[(ch - 18) * 64 + e];
  }
  if (tid < 54) bias_l[tid] = (tid < 18) ? bcls[tid] : bbox[tid - 18];
  __syncthreads();

  const int w = tid & 31, chg = tid >> 5;
  const int cnt = (chg < 6) ? 7 : 6;
  float acc[7] = {0.f, 0.f, 0.f, 0.f, 0.f, 0.f, 0.f};
  for (int e2 = 0; e2 < 32; e2++) {
    const float2 m2 = *(const float2*)&mrg_l[w][e2 * 2];
    #pragma unroll
    for (int i = 0; i < 7; i++) {
      if (i < cnt) {
        const int ch = chg + 8 * i;
        const float2 wv = *(const float2*)&wcb_l[ch][e2 * 2];
        acc[i] = fmaf(m2.x, wv.x, acc[i]);
        acc[i] = fmaf(m2.y, wv.y, acc[i]);
      }
    }
  }
  #pragma unroll
  for (int i = 0; i < 7; i++) {
    if (i < cnt) {
      const int ch = chg + 8 * i;
      const float v = acc[i] + bias_l[ch];
      if (ch < 18) logits[ch][w] = v;
      else out[36864 + n * 36864 + (ch - 18) * 1024 + h * 32 + w] = v;
    }
  }
  __syncthreads();
  for (int idx = tid; idx < 576; idx += 256) {
    const int ch = idx >> 5, w2 = idx & 31;
    const float a = logits[ch][w2];
    const float b = logits[(ch + 9) % 18][w2];
    const float m = fmaxf(a, b);
    const float ea = expf(a - m), eb = expf(b - m);
    out[n * 18432 + ch * 1024 + h * 32 + w2] = ea / (ea + eb);
  }
}

extern "C" void kernel_launch(void* const* d_in, const int* in_sizes, int n_in,
                              void* d_out, int out_size, void* d_ws, size_t ws_size,
                              hipStream_t stream) {
  (void)in_sizes; (void)n_in; (void)out_size; (void)ws_size;
  const float* target_feat   = (const float*)d_in[0];
  const float* template_feat = (const float*)d_in[1];
  const float* w_target      = (const float*)d_in[2];
  const float* b_target      = (const float*)d_in[3];
  const float* bn_gamma      = (const float*)d_in[4];
  const float* bn_beta       = (const float*)d_in[5];
  const float* bn_mean       = (const float*)d_in[6];
  const float* bn_var        = (const float*)d_in[7];
  const float* w_template    = (const float*)d_in[8];
  const float* b_template    = (const float*)d_in[9];
  const float* w_merge       = (const float*)d_in[10];
  const float* corr_bias     = (const float*)d_in[11];
  const float* w_cls         = (const float*)d_in[12];
  const float* b_cls         = (const float*)d_in[13];
  const float* w_box         = (const float*)d_in[14];
  const float* b_box         = (const float*)d_in[15];
  float* ws = (float*)d_ws;
  float* out = (float*)d_out;

  hipLaunchKernelGGL(k_fold, dim3(2304), dim3(256), 0, stream,
                     w_template, w_merge, ws);
  hipLaunchKernelGGL(k0_prep, dim3(2048), dim3(256), 0, stream,
                     target_feat, w_merge, b_template, ws);
  hipLaunchKernelGGL(k_conv, dim3(2048), dim3(256), 0, stream,
                     w_target, ws);
  hipLaunchKernelGGL(k_cred, dim3(256), dim3(256), 0, stream,
                     b_target, bn_gamma, bn_beta, bn_mean, bn_var, ws);
  hipLaunchKernelGGL(k2_z2, dim3(64), dim3(256), 0, stream,
                     template_feat, ws);
  hipLaunchKernelGGL(k3_merged, dim3(256), dim3(128), 0, stream, ws);
  hipLaunchKernelGGL(k4_heads, dim3(64), dim3(256), 0, stream,
                     corr_bias, w_cls, b_cls, w_box, b_box, ws, out);
}